// Round 7
// baseline (381.040 us; speedup 1.0000x reference)
//
#include <hip/hip_runtime.h>
#include <hip/hip_bf16.h>
#include <stdint.h>

#define S_LEN 4096
#define DM 1024
#define NH 16
#define DKH 64
#define LDQ (3 * DM)

typedef __attribute__((ext_vector_type(8))) __bf16 bf16x8;
typedef __attribute__((ext_vector_type(8))) short s16x8;
typedef __attribute__((ext_vector_type(4))) float f32x4;

__device__ inline unsigned short f2bf(float f) {
  unsigned int u = __builtin_bit_cast(unsigned int, f);
  u += 0x7fff + ((u >> 16) & 1);   // RNE
  return (unsigned short)(u >> 16);
}
__device__ inline float bf2f(unsigned short u) {
  return __builtin_bit_cast(float, (unsigned int)u << 16);
}
__device__ inline unsigned short f2bf_hw(float f) {   // v_cvt single-op path
  return __builtin_bit_cast(unsigned short, __float2bfloat16(f));
}

__device__ inline f32x4 mfma16(s16x8 a, s16x8 b, f32x4 c) {
  return __builtin_amdgcn_mfma_f32_16x16x32_bf16(
      __builtin_bit_cast(bf16x8, a), __builtin_bit_cast(bf16x8, b), c, 0, 0, 0);
}

__device__ inline void gld_lds16(const unsigned short* g, unsigned short* l) {
  __builtin_amdgcn_global_load_lds(
      (const __attribute__((address_space(1))) unsigned int*)g,
      (__attribute__((address_space(3))) unsigned int*)l, 16, 0, 0);
}

__global__ void convert_f32_bf16(const float* __restrict__ in,
                                 unsigned short* __restrict__ out, int n4) {
  int i = blockIdx.x * blockDim.x + threadIdx.x;
  if (i >= n4) return;
  float4 v = reinterpret_cast<const float4*>(in)[i];
  ushort4 o;
  o.x = f2bf(v.x); o.y = f2bf(v.y); o.z = f2bf(v.z); o.w = f2bf(v.w);
  reinterpret_cast<ushort4*>(out)[i] = o;
}

__device__ inline void storeC(unsigned short* C, size_t i, float v) { C[i] = f2bf(v); }
__device__ inline void storeC(float* C, size_t i, float v) { C[i] = v; }

// C[m][n] = sum_k A[m][k] * B[n][k]
template <typename OutT>
__global__ __launch_bounds__(256) void gemm_bt(const unsigned short* __restrict__ A,
                                               const unsigned short* __restrict__ B,
                                               OutT* __restrict__ C, int M, int N, int K) {
  __shared__ __align__(16) unsigned short lds_a[128 * 64];
  __shared__ __align__(16) unsigned short lds_b[128 * 64];
  const int tid = threadIdx.x;
  const int lane = tid & 63;
  const int w = tid >> 6;
  const int wr = w >> 1, wc = w & 1;
  const int l15 = lane & 15, lhi = lane >> 4;
  const int bm0 = blockIdx.x * 128, bn0 = blockIdx.y * 128;
  const int srow = lane >> 3;
  const int scol = (lane & 7) * 8;

  f32x4 acc[4][4] = {};

  for (int k0 = 0; k0 < K; k0 += 64) {
    __syncthreads();
#pragma unroll
    for (int i = 0; i < 4; ++i) {
      const int base = i * 2048 + w * 512;
      const int row = i * 32 + w * 8 + srow;
      gld_lds16(A + (size_t)(bm0 + row) * K + k0 + scol, lds_a + base);
      gld_lds16(B + (size_t)(bn0 + row) * K + k0 + scol, lds_b + base);
    }
    __syncthreads();
#pragma unroll
    for (int kk = 0; kk < 2; ++kk) {
      s16x8 af[4], bfr[4];
#pragma unroll
      for (int mi = 0; mi < 4; ++mi)
        af[mi] = *(const s16x8*)&lds_a[(wr * 64 + mi * 16 + l15) * 64 + kk * 32 + lhi * 8];
#pragma unroll
      for (int ni = 0; ni < 4; ++ni)
        bfr[ni] = *(const s16x8*)&lds_b[(wc * 64 + ni * 16 + l15) * 64 + kk * 32 + lhi * 8];
#pragma unroll
      for (int mi = 0; mi < 4; ++mi)
#pragma unroll
        for (int ni = 0; ni < 4; ++ni)
          acc[mi][ni] = mfma16(af[mi], bfr[ni], acc[mi][ni]);
    }
  }
#pragma unroll
  for (int mi = 0; mi < 4; ++mi)
#pragma unroll
    for (int ni = 0; ni < 4; ++ni)
#pragma unroll
      for (int r = 0; r < 4; ++r) {
        int row = bm0 + wr * 64 + mi * 16 + lhi * 4 + r;
        int col = bn0 + wc * 64 + ni * 16 + l15;
        storeC(C, (size_t)row * N + col, acc[mi][ni][r]);
      }
}

// V^T per head: vTg[(h*DKH + dk)*S + s] = QKV[s][2*DM + h*DKH + dk]
__global__ __launch_bounds__(256) void transpose_v(const unsigned short* __restrict__ QKV,
                                                   unsigned short* __restrict__ vTg) {
  const int s0 = blockIdx.x * 64;
  const int h = blockIdx.y;
  __shared__ __align__(16) unsigned short t[64][72];
  const int r = threadIdx.x >> 2;
  const int c = (threadIdx.x & 3) * 16;
  const unsigned short* src = QKV + (size_t)(s0 + r) * LDQ + 2 * DM + h * DKH + c;
#pragma unroll
  for (int j = 0; j < 16; j += 4)
    *(ushort4*)&t[r][c + j] = *(const ushort4*)(src + j);
  __syncthreads();
  const int d = threadIdx.x >> 2;
  const int sc = (threadIdx.x & 3) * 16;
  unsigned short* dst = vTg + (size_t)(h * DKH + d) * S_LEN + s0 + sc;
#pragma unroll
  for (int j = 0; j < 16; j += 4) {
    ushort4 v;
    v.x = t[sc + j + 0][d]; v.y = t[sc + j + 1][d];
    v.z = t[sc + j + 2][d]; v.w = t[sc + j + 3][d];
    *(ushort4*)(dst + j) = v;
  }
}

// Cooperative async staging of one 64x64 K-tile and V^T-tile into LDS.
// Linear LDS dest; SOURCE column pre-swizzled so reads at col^((row&7)*8)
// return the true (row,col).
__device__ inline void stage_kv(const unsigned short* __restrict__ Kp,
                                const unsigned short* __restrict__ vTg,
                                unsigned short* lk, unsigned short* lv,
                                int kb, int h, int tid) {
  const int w = tid >> 6, l = tid & 63;
  const int sub = l >> 3;                       // 0..7
  const int src_col = 8 * ((l & 7) ^ sub);      // pre-swizzled source column
#pragma unroll
  for (int i = 0; i < 2; ++i) {
    const int row = i * 32 + w * 8 + sub;
    gld_lds16(Kp + (size_t)(kb + row) * LDQ + h * DKH + src_col,
              lk + (i * 32 + w * 8) * 64);
    gld_lds16(vTg + (size_t)(h * DKH + row) * S_LEN + kb + src_col,
              lv + (i * 32 + w * 8) * 64);
  }
}

// one k-tile of flash attention for one wave (16 q-rows), operands from LDS.
// pbuf is [16][64] XOR-swizzled (no pad): elem col' = col ^ ((row&7)*8).
template <bool MASK>
__device__ inline void attn_tile_lds(const unsigned short* __restrict__ lk,
                                     const unsigned short* __restrict__ lv,
                                     unsigned short (*pb)[64], const s16x8 qf[2],
                                     int kb, int qrow0, int l15, int lhi,
                                     f32x4 o[4], float m_r[4], float l_r[4]) {
  const int sw = (l15 & 7) * 8;   // XOR swizzle for this lane's row reads
  f32x4 sf[4];
#pragma unroll
  for (int st = 0; st < 4; ++st) {
    f32x4 acc = {};
#pragma unroll
    for (int kk = 0; kk < 2; ++kk) {
      s16x8 kf = *(const s16x8*)&lk[(st * 16 + l15) * 64 + ((kk * 32 + lhi * 8) ^ sw)];
      acc = mfma16(qf[kk], kf, acc);
    }
    sf[st] = acc;
  }
  if (MASK) {
#pragma unroll
    for (int st = 0; st < 4; ++st) {
      const int key = kb + st * 16 + l15;
#pragma unroll
      for (int r = 0; r < 4; ++r) {
        const int qrow = qrow0 + lhi * 4 + r;
        if (key > qrow) sf[st][r] = -1e30f;
      }
    }
  }
  // per-row tile max
  float mt[4];
#pragma unroll
  for (int r = 0; r < 4; ++r) {
    float mx = fmaxf(fmaxf(sf[0][r], sf[1][r]), fmaxf(sf[2][r], sf[3][r]));
#pragma unroll
    for (int d = 1; d < 16; d <<= 1) mx = fmaxf(mx, __shfl_xor(mx, d));
    mt[r] = mx;
  }
  // defer-max (T13): only rescale when some row's max grew by > 8
  int grow = (mt[0] > m_r[0] + 8.f) | (mt[1] > m_r[1] + 8.f) |
             (mt[2] > m_r[2] + 8.f) | (mt[3] > m_r[3] + 8.f);
  const bool anyg = __any(grow);
  float alpha[4];
  if (anyg) {
#pragma unroll
    for (int r = 0; r < 4; ++r) {
      const float mn = fmaxf(m_r[r], mt[r]);
      alpha[r] = __expf(m_r[r] - mn);
      m_r[r] = mn;
    }
  }
  // exp + row-sum (P bounded by e^8 on the fast path; f32/bf16 safe)
#pragma unroll
  for (int r = 0; r < 4; ++r) {
    float rs = 0.f;
#pragma unroll
    for (int st = 0; st < 4; ++st) {
      const float p = __expf(sf[st][r] - m_r[r]);
      sf[st][r] = p;
      rs += p;
    }
#pragma unroll
    for (int d = 1; d < 16; d <<= 1) rs += __shfl_xor(rs, d);
    l_r[r] = (anyg ? l_r[r] * alpha[r] : l_r[r]) + rs;
  }
  if (anyg) {
#pragma unroll
    for (int n = 0; n < 4; ++n)
#pragma unroll
      for (int r = 0; r < 4; ++r) o[n][r] *= alpha[r];
  }
  // P -> wave-private swizzled LDS (intra-wave ds write->read, no barrier)
#pragma unroll
  for (int st = 0; st < 4; ++st)
#pragma unroll
    for (int r = 0; r < 4; ++r) {
      const int row = lhi * 4 + r;
      pb[row][(st * 16 + l15) ^ ((row & 7) * 8)] = f2bf_hw(sf[st][r]);
    }
#pragma unroll
  for (int kk = 0; kk < 2; ++kk) {
    s16x8 pa = *(const s16x8*)&pb[l15][(kk * 32 + lhi * 8) ^ sw];
#pragma unroll
    for (int n = 0; n < 4; ++n) {
      s16x8 vb = *(const s16x8*)&lv[(n * 16 + l15) * 64 + ((kk * 32 + lhi * 8) ^ sw)];
      o[n] = mfma16(pa, vb, o[n]);
    }
  }
}

// grid (64, NH) = 1024 blocks, 4/CU (LDS = 40960 = 163840/4 exactly).
// Mapping: adjacent within-XCD indices pair qt {k, 63-k} (balanced under
// sequential CU fill); each XCD owns 2 heads (2 MB K+V^T fits its 4 MB L2).
__global__ __launch_bounds__(256) void attn_causal4(const unsigned short* __restrict__ QKV,
                                                    const unsigned short* __restrict__ vTg,
                                                    unsigned short* __restrict__ CTX) {
  const int flat = blockIdx.x + 64 * blockIdx.y;   // 0..1023
  const int xcd = flat & 7;
  const int t = flat >> 3;            // 0..127 within XCD
  const int hb = t & 1;
  const int j = t >> 1;               // 0..63
  const int qt = (j & 1) ? (63 - (j >> 1)) : (j >> 1);
  const int h = 2 * xcd + hb;
  const int tid = threadIdx.x;
  const int lane = tid & 63, w = tid >> 6;
  const int l15 = lane & 15, lhi = lane >> 4;
  const int qrow0 = qt * 64 + w * 16;

  __shared__ __align__(16) unsigned short lk[2][64 * 64];   // 16 KiB
  __shared__ __align__(16) unsigned short lv[2][64 * 64];   // 16 KiB
  __shared__ __align__(16) unsigned short pbuf[4][16][64];  //  8 KiB
  unsigned short (*pb)[64] = pbuf[w];

  const unsigned short* Qp = QKV;
  const unsigned short* Kp = QKV + DM;

  s16x8 qf[2];
#pragma unroll
  for (int kk = 0; kk < 2; ++kk) {
    s16x8 q = *(const s16x8*)&Qp[(size_t)(qrow0 + l15) * LDQ + h * DKH + kk * 32 + lhi * 8];
#pragma unroll
    for (int e = 0; e < 8; ++e)
      q[e] = (short)f2bf(bf2f((unsigned short)q[e]) * 0.125f);  // fold 1/sqrt(64), exact
    qf[kk] = q;
  }
  f32x4 o[4] = {};
  float m_r[4], l_r[4];
#pragma unroll
  for (int r = 0; r < 4; ++r) { m_r[r] = -1e30f; l_r[r] = 0.f; }

  stage_kv(Kp, vTg, lk[0], lv[0], 0, h, tid);
  int cur = 0;
#pragma unroll 1
  for (int kbi = 0; kbi <= qt; ++kbi) {
    __syncthreads();             // staged buf[cur] ready (vmcnt drained at barrier)
    if (kbi < qt)
      stage_kv(Kp, vTg, lk[cur ^ 1], lv[cur ^ 1], (kbi + 1) * 64, h, tid);
    if (kbi < qt)
      attn_tile_lds<false>(lk[cur], lv[cur], pb, qf, kbi * 64, qrow0, l15, lhi, o, m_r, l_r);
    else
      attn_tile_lds<true>(lk[cur], lv[cur], pb, qf, kbi * 64, qrow0, l15, lhi, o, m_r, l_r);
    cur ^= 1;
  }

#pragma unroll
  for (int n = 0; n < 4; ++n)
#pragma unroll
    for (int r = 0; r < 4; ++r) {
      const int qrow = qrow0 + lhi * 4 + r;
      CTX[(size_t)qrow * DM + h * DKH + n * 16 + l15] = f2bf_hw(o[n][r] / l_r[r]);
    }
}

extern "C" void kernel_launch(void* const* d_in, const int* in_sizes, int n_in,
                              void* d_out, int out_size, void* d_ws, size_t ws_size,
                              hipStream_t stream) {
  const float* x  = (const float*)d_in[0];
  const float* Wq = (const float*)d_in[1];
  const float* Wk = (const float*)d_in[2];
  const float* Wv = (const float*)d_in[3];
  const float* Wo = (const float*)d_in[4];
  float* out = (float*)d_out;
  char* ws = (char*)d_ws;

  unsigned short* x_bf  = (unsigned short*)(ws + 0);
  unsigned short* wqkv  = (unsigned short*)(ws + (size_t)8 * 1024 * 1024);
  unsigned short* wo_bf = (unsigned short*)(ws + (size_t)14 * 1024 * 1024);
  unsigned short* qkv   = (unsigned short*)(ws + (size_t)16 * 1024 * 1024);
  unsigned short* ctx   = (unsigned short*)(ws + (size_t)40 * 1024 * 1024);
  unsigned short* vTg   = (unsigned short*)(ws + (size_t)48 * 1024 * 1024);

  const int n4x = S_LEN * DM / 4;
  convert_f32_bf16<<<(n4x + 255) / 256, 256, 0, stream>>>(x, x_bf, n4x);
  const int w4 = DM * DM / 4;
  convert_f32_bf16<<<(w4 + 255) / 256, 256, 0, stream>>>(Wq, wqkv, w4);
  convert_f32_bf16<<<(w4 + 255) / 256, 256, 0, stream>>>(Wk, wqkv + DM * DM, w4);
  convert_f32_bf16<<<(w4 + 255) / 256, 256, 0, stream>>>(Wv, wqkv + 2 * DM * DM, w4);
  convert_f32_bf16<<<(w4 + 255) / 256, 256, 0, stream>>>(Wo, wo_bf, w4);

  dim3 g1(S_LEN / 128, (3 * DM) / 128);
  gemm_bt<unsigned short><<<g1, 256, 0, stream>>>(x_bf, wqkv, qkv, S_LEN, 3 * DM, DM);

  dim3 gt(S_LEN / 64, NH);
  transpose_v<<<gt, 256, 0, stream>>>(qkv, vTg);

  dim3 g2(64, NH);
  attn_causal4<<<g2, 256, 0, stream>>>(qkv, vTg, ctx);

  dim3 g3(S_LEN / 128, DM / 128);
  gemm_bt<float><<<g3, 256, 0, stream>>>(ctx, wo_bf, out, S_LEN, DM, DM);
}

// Round 8
// 294.370 us; speedup vs baseline: 1.2944x; 1.2944x over previous
//
#include <hip/hip_runtime.h>
#include <hip/hip_bf16.h>
#include <stdint.h>

#define S_LEN 4096
#define DM 1024
#define NH 16
#define DKH 64
#define LDQ (3 * DM)

typedef __attribute__((ext_vector_type(8))) __bf16 bf16x8;
typedef __attribute__((ext_vector_type(8))) short s16x8;
typedef __attribute__((ext_vector_type(4))) float f32x4;

__device__ inline unsigned short f2bf(float f) {
  unsigned int u = __builtin_bit_cast(unsigned int, f);
  u += 0x7fff + ((u >> 16) & 1);   // RNE
  return (unsigned short)(u >> 16);
}
__device__ inline float bf2f(unsigned short u) {
  return __builtin_bit_cast(float, (unsigned int)u << 16);
}
__device__ inline unsigned short f2bf_hw(float f) {   // v_cvt single-op path
  return __builtin_bit_cast(unsigned short, __float2bfloat16(f));
}

__device__ inline f32x4 mfma16(s16x8 a, s16x8 b, f32x4 c) {
  return __builtin_amdgcn_mfma_f32_16x16x32_bf16(
      __builtin_bit_cast(bf16x8, a), __builtin_bit_cast(bf16x8, b), c, 0, 0, 0);
}

__device__ inline void gld_lds16(const unsigned short* g, unsigned short* l) {
  __builtin_amdgcn_global_load_lds(
      (const __attribute__((address_space(1))) unsigned int*)g,
      (__attribute__((address_space(3))) unsigned int*)l, 16, 0, 0);
}

// one fused conversion pass: x (4M elems) + Wq/Wk/Wv (-> wqkv) + Wo (-> wo_bf)
__global__ __launch_bounds__(256) void convert_all(
    const float* __restrict__ x, const float* __restrict__ wq,
    const float* __restrict__ wk, const float* __restrict__ wv,
    const float* __restrict__ wo, unsigned short* __restrict__ x_bf,
    unsigned short* __restrict__ wqkv, unsigned short* __restrict__ wo_bf) {
  const int XF4 = (S_LEN * DM) / 4;   // 1048576
  const int WF4 = (DM * DM) / 4;      // 262144
  int i = blockIdx.x * blockDim.x + threadIdx.x;   // grid sized exactly
  const float* src;
  unsigned short* dst;
  int off;
  if (i < XF4) { src = x; dst = x_bf; off = i; }
  else {
    int j = i - XF4;
    if (j < WF4)          { src = wq; dst = wqkv;              off = j; }
    else if (j < 2 * WF4) { src = wk; dst = wqkv + DM * DM;    off = j - WF4; }
    else if (j < 3 * WF4) { src = wv; dst = wqkv + 2 * DM * DM; off = j - 2 * WF4; }
    else                  { src = wo; dst = wo_bf;             off = j - 3 * WF4; }
  }
  float4 v = reinterpret_cast<const float4*>(src)[off];
  ushort4 o;
  o.x = f2bf(v.x); o.y = f2bf(v.y); o.z = f2bf(v.z); o.w = f2bf(v.w);
  reinterpret_cast<ushort4*>(dst)[off] = o;
}

__device__ inline void storeC(unsigned short* C, size_t i, float v) { C[i] = f2bf(v); }
__device__ inline void storeC(float* C, size_t i, float v) { C[i] = v; }

// C[m][n] = sum_k A[m][k] * B[n][k]
template <typename OutT>
__global__ __launch_bounds__(256) void gemm_bt(const unsigned short* __restrict__ A,
                                               const unsigned short* __restrict__ B,
                                               OutT* __restrict__ C, int M, int N, int K) {
  __shared__ __align__(16) unsigned short lds_a[128 * 64];
  __shared__ __align__(16) unsigned short lds_b[128 * 64];
  const int tid = threadIdx.x;
  const int lane = tid & 63;
  const int w = tid >> 6;
  const int wr = w >> 1, wc = w & 1;
  const int l15 = lane & 15, lhi = lane >> 4;
  const int bm0 = blockIdx.x * 128, bn0 = blockIdx.y * 128;
  const int srow = lane >> 3;
  const int scol = (lane & 7) * 8;

  f32x4 acc[4][4] = {};

  for (int k0 = 0; k0 < K; k0 += 64) {
    __syncthreads();
#pragma unroll
    for (int i = 0; i < 4; ++i) {
      const int base = i * 2048 + w * 512;
      const int row = i * 32 + w * 8 + srow;
      gld_lds16(A + (size_t)(bm0 + row) * K + k0 + scol, lds_a + base);
      gld_lds16(B + (size_t)(bn0 + row) * K + k0 + scol, lds_b + base);
    }
    __syncthreads();
#pragma unroll
    for (int kk = 0; kk < 2; ++kk) {
      s16x8 af[4], bfr[4];
#pragma unroll
      for (int mi = 0; mi < 4; ++mi)
        af[mi] = *(const s16x8*)&lds_a[(wr * 64 + mi * 16 + l15) * 64 + kk * 32 + lhi * 8];
#pragma unroll
      for (int ni = 0; ni < 4; ++ni)
        bfr[ni] = *(const s16x8*)&lds_b[(wc * 64 + ni * 16 + l15) * 64 + kk * 32 + lhi * 8];
#pragma unroll
      for (int mi = 0; mi < 4; ++mi)
#pragma unroll
        for (int ni = 0; ni < 4; ++ni)
          acc[mi][ni] = mfma16(af[mi], bfr[ni], acc[mi][ni]);
    }
  }
#pragma unroll
  for (int mi = 0; mi < 4; ++mi)
#pragma unroll
    for (int ni = 0; ni < 4; ++ni)
#pragma unroll
      for (int r = 0; r < 4; ++r) {
        int row = bm0 + wr * 64 + mi * 16 + lhi * 4 + r;
        int col = bn0 + wc * 64 + ni * 16 + l15;
        storeC(C, (size_t)row * N + col, acc[mi][ni][r]);
      }
}

// V^T per head: vTg[(h*DKH + dk)*S + s] = QKV[s][2*DM + h*DKH + dk]
__global__ __launch_bounds__(256) void transpose_v(const unsigned short* __restrict__ QKV,
                                                   unsigned short* __restrict__ vTg) {
  const int s0 = blockIdx.x * 64;
  const int h = blockIdx.y;
  __shared__ __align__(16) unsigned short t[64][72];
  const int r = threadIdx.x >> 2;
  const int c = (threadIdx.x & 3) * 16;
  const unsigned short* src = QKV + (size_t)(s0 + r) * LDQ + 2 * DM + h * DKH + c;
#pragma unroll
  for (int j = 0; j < 16; j += 4)
    *(ushort4*)&t[r][c + j] = *(const ushort4*)(src + j);
  __syncthreads();
  const int d = threadIdx.x >> 2;
  const int sc = (threadIdx.x & 3) * 16;
  unsigned short* dst = vTg + (size_t)(h * DKH + d) * S_LEN + s0 + sc;
#pragma unroll
  for (int j = 0; j < 16; j += 4) {
    ushort4 v;
    v.x = t[sc + j + 0][d]; v.y = t[sc + j + 1][d];
    v.z = t[sc + j + 2][d]; v.w = t[sc + j + 3][d];
    *(ushort4*)(dst + j) = v;
  }
}

// Cooperative async staging of one 64x64 K-tile and V^T-tile into LDS.
// Linear LDS dest; SOURCE column pre-swizzled so reads at col^((row&7)*8)
// return the true (row,col).
__device__ inline void stage_kv(const unsigned short* __restrict__ Kp,
                                const unsigned short* __restrict__ vTg,
                                unsigned short* lk, unsigned short* lv,
                                int kb, int h, int tid) {
  const int w = tid >> 6, l = tid & 63;
  const int sub = l >> 3;                       // 0..7
  const int src_col = 8 * ((l & 7) ^ sub);      // pre-swizzled source column
#pragma unroll
  for (int i = 0; i < 2; ++i) {
    const int row = i * 32 + w * 8 + sub;
    gld_lds16(Kp + (size_t)(kb + row) * LDQ + h * DKH + src_col,
              lk + (i * 32 + w * 8) * 64);
    gld_lds16(vTg + (size_t)(h * DKH + row) * S_LEN + kb + src_col,
              lv + (i * 32 + w * 8) * 64);
  }
}

// one k-tile of flash attention for one wave (16 q-rows), operands from LDS.
// pbuf is [16][64] XOR-swizzled (no pad): elem col' = col ^ ((row&7)*8).
template <bool MASK>
__device__ inline void attn_tile_lds(const unsigned short* __restrict__ lk,
                                     const unsigned short* __restrict__ lv,
                                     unsigned short (*pb)[64], const s16x8 qf[2],
                                     int kb, int qrow0, int l15, int lhi,
                                     f32x4 o[4], float m_r[4], float l_r[4]) {
  const int sw = (l15 & 7) * 8;   // XOR swizzle for this lane's row reads
  f32x4 sf[4];
#pragma unroll
  for (int st = 0; st < 4; ++st) {
    f32x4 acc = {};
#pragma unroll
    for (int kk = 0; kk < 2; ++kk) {
      s16x8 kf = *(const s16x8*)&lk[(st * 16 + l15) * 64 + ((kk * 32 + lhi * 8) ^ sw)];
      acc = mfma16(qf[kk], kf, acc);
    }
    sf[st] = acc;
  }
  if (MASK) {
#pragma unroll
    for (int st = 0; st < 4; ++st) {
      const int key = kb + st * 16 + l15;
#pragma unroll
      for (int r = 0; r < 4; ++r) {
        const int qrow = qrow0 + lhi * 4 + r;
        if (key > qrow) sf[st][r] = -1e30f;
      }
    }
  }
  // per-row tile max
  float mt[4];
#pragma unroll
  for (int r = 0; r < 4; ++r) {
    float mx = fmaxf(fmaxf(sf[0][r], sf[1][r]), fmaxf(sf[2][r], sf[3][r]));
#pragma unroll
    for (int d = 1; d < 16; d <<= 1) mx = fmaxf(mx, __shfl_xor(mx, d));
    mt[r] = mx;
  }
  // defer-max (T13): only rescale when some row's max grew by > 8
  int grow = (mt[0] > m_r[0] + 8.f) | (mt[1] > m_r[1] + 8.f) |
             (mt[2] > m_r[2] + 8.f) | (mt[3] > m_r[3] + 8.f);
  const bool anyg = __any(grow);
  float alpha[4];
  if (anyg) {
#pragma unroll
    for (int r = 0; r < 4; ++r) {
      const float mn = fmaxf(m_r[r], mt[r]);
      alpha[r] = __expf(m_r[r] - mn);
      m_r[r] = mn;
    }
  }
  // exp + row-sum (P bounded by e^8 on the fast path; f32/bf16 safe)
#pragma unroll
  for (int r = 0; r < 4; ++r) {
    float rs = 0.f;
#pragma unroll
    for (int st = 0; st < 4; ++st) {
      const float p = __expf(sf[st][r] - m_r[r]);
      sf[st][r] = p;
      rs += p;
    }
#pragma unroll
    for (int d = 1; d < 16; d <<= 1) rs += __shfl_xor(rs, d);
    l_r[r] = (anyg ? l_r[r] * alpha[r] : l_r[r]) + rs;
  }
  if (anyg) {
#pragma unroll
    for (int n = 0; n < 4; ++n)
#pragma unroll
      for (int r = 0; r < 4; ++r) o[n][r] *= alpha[r];
  }
  // P -> wave-private swizzled LDS (intra-wave ds write->read, no barrier)
#pragma unroll
  for (int st = 0; st < 4; ++st)
#pragma unroll
    for (int r = 0; r < 4; ++r) {
      const int row = lhi * 4 + r;
      pb[row][(st * 16 + l15) ^ ((row & 7) * 8)] = f2bf_hw(sf[st][r]);
    }
#pragma unroll
  for (int kk = 0; kk < 2; ++kk) {
    s16x8 pa = *(const s16x8*)&pb[l15][(kk * 32 + lhi * 8) ^ sw];
#pragma unroll
    for (int n = 0; n < 4; ++n) {
      s16x8 vb = *(const s16x8*)&lv[(n * 16 + l15) * 64 + ((kk * 32 + lhi * 8) ^ sw)];
      o[n] = mfma16(pa, vb, o[n]);
    }
  }
}

// Split+pair uniform schedule: 1024 blocks, each processes TWO k-segments:
// (qt=p, seg=b) then (qt=63-p, seg=1-b), total 32-33 k-tiles per block.
// Segments write partial (o, m, l); merge kernel combines.
// seg0 of qt = k-tiles [0, (qt+2)>>1), seg1 = [(qt+2)>>1, qt+1).
__global__ __launch_bounds__(256, 4) void attn_split(const unsigned short* __restrict__ QKV,
                                                     const unsigned short* __restrict__ vTg,
                                                     unsigned short* __restrict__ po0,
                                                     unsigned short* __restrict__ po1,
                                                     float2* __restrict__ ml) {
  const int flat = blockIdx.x;          // 0..1023
  const int xcd = flat & 7;
  const int t = flat >> 3;              // 0..127
  const int h = 2 * xcd + (t & 1);      // 2 heads per XCD (L2 locality)
  const int u = t >> 1;                 // 0..63
  const int p = u & 31;
  const int b = u >> 5;
  const int tid = threadIdx.x;
  const int lane = tid & 63, w = tid >> 6;
  const int l15 = lane & 15, lhi = lane >> 4;

  __shared__ __align__(16) unsigned short lk[2][64 * 64];   // 16 KiB
  __shared__ __align__(16) unsigned short lv[2][64 * 64];   // 16 KiB
  __shared__ __align__(16) unsigned short pbuf[4][16][64];  //  8 KiB -> 40960 total
  unsigned short (*pb)[64] = pbuf[w];

  const unsigned short* Qp = QKV;
  const unsigned short* Kp = QKV + DM;

#pragma unroll 1
  for (int mem = 0; mem < 2; ++mem) {
    const int qt  = mem ? (63 - p) : p;
    const int seg = mem ? (1 - b) : b;
    const int s0 = (qt + 2) >> 1;
    const int ks = seg ? s0 : 0;
    const int ke = seg ? (qt + 1) : s0;
    const int qrow0 = qt * 64 + w * 16;

    s16x8 qf[2];
#pragma unroll
    for (int kk = 0; kk < 2; ++kk) {
      s16x8 q = *(const s16x8*)&Qp[(size_t)(qrow0 + l15) * LDQ + h * DKH + kk * 32 + lhi * 8];
#pragma unroll
      for (int e = 0; e < 8; ++e)
        q[e] = (short)f2bf(bf2f((unsigned short)q[e]) * 0.125f);  // fold 1/sqrt(64), exact
      qf[kk] = q;
    }
    f32x4 o[4] = {};
    float m_r[4], l_r[4];
#pragma unroll
    for (int r = 0; r < 4; ++r) { m_r[r] = -1e30f; l_r[r] = 0.f; }

    __syncthreads();               // buffers free (previous member done reading)
    if (ks < ke) {
      stage_kv(Kp, vTg, lk[0], lv[0], ks * 64, h, tid);
      int cur = 0;
#pragma unroll 1
      for (int kbi = ks; kbi < ke; ++kbi) {
        __syncthreads();           // staged buf[cur] ready (vmcnt drained at barrier)
        if (kbi + 1 < ke)
          stage_kv(Kp, vTg, lk[cur ^ 1], lv[cur ^ 1], (kbi + 1) * 64, h, tid);
        if (kbi == qt)
          attn_tile_lds<true>(lk[cur], lv[cur], pb, qf, kbi * 64, qrow0, l15, lhi, o, m_r, l_r);
        else
          attn_tile_lds<false>(lk[cur], lv[cur], pb, qf, kbi * 64, qrow0, l15, lhi, o, m_r, l_r);
        cur ^= 1;
      }
    }
    // epilogue: unnormalized partial o (bf16) + (m, l)
    unsigned short* po = seg ? po1 : po0;
#pragma unroll
    for (int n = 0; n < 4; ++n)
#pragma unroll
      for (int r = 0; r < 4; ++r) {
        const int qrow = qrow0 + lhi * 4 + r;
        po[(size_t)qrow * DM + h * DKH + n * 16 + l15] = f2bf_hw(o[n][r]);
      }
    if (l15 == 0) {
#pragma unroll
      for (int r = 0; r < 4; ++r) {
        const int qrow = qrow0 + lhi * 4 + r;
        ml[(qrow * NH + h) * 2 + seg] = make_float2(m_r[r], l_r[r]);
      }
    }
  }
}

// merge: ctx[row, h*64+c] = (o0*e^{m0-m} + o1*e^{m1-m}) / (l0*e^{m0-m} + l1*e^{m1-m})
// po1 IS the ctx buffer (element-wise in-place).
__global__ __launch_bounds__(256) void merge_parts(const unsigned short* __restrict__ po0,
                                                   unsigned short* __restrict__ po1_ctx,
                                                   const float2* __restrict__ ml) {
  const int i = blockIdx.x * blockDim.x + threadIdx.x;   // 0..65535
  const int row = i >> 4, h = i & 15;
  const float2 ml0 = ml[i * 2 + 0];
  const float2 ml1 = ml[i * 2 + 1];
  const float m = fmaxf(ml0.x, ml1.x);
  const float f0 = __expf(ml0.x - m);
  const float f1 = __expf(ml1.x - m);
  const float rl = 1.f / (ml0.y * f0 + ml1.y * f1);
  const size_t base = (size_t)row * DM + h * DKH;
#pragma unroll
  for (int c = 0; c < DKH; c += 8) {
    s16x8 a = *(const s16x8*)(po0 + base + c);
    s16x8 bb = *(const s16x8*)(po1_ctx + base + c);
    s16x8 out;
#pragma unroll
    for (int j = 0; j < 8; ++j)
      out[j] = (short)f2bf_hw((bf2f((unsigned short)a[j]) * f0 +
                               bf2f((unsigned short)bb[j]) * f1) * rl);
    *(s16x8*)(po1_ctx + base + c) = out;
  }
}

extern "C" void kernel_launch(void* const* d_in, const int* in_sizes, int n_in,
                              void* d_out, int out_size, void* d_ws, size_t ws_size,
                              hipStream_t stream) {
  const float* x  = (const float*)d_in[0];
  const float* Wq = (const float*)d_in[1];
  const float* Wk = (const float*)d_in[2];
  const float* Wv = (const float*)d_in[3];
  const float* Wo = (const float*)d_in[4];
  float* out = (float*)d_out;
  char* ws = (char*)d_ws;

  // [0,8): x_bf, later reused as partial-o seg0 (x_bf dead after gemm1)
  // [8,14): wqkv, later [8,9) reused as ml (wqkv dead after gemm1)
  // [14,16): wo_bf (live until gemm3)
  // [16,40): qkv   [40,48): ctx == partial-o seg1   [48,64): vTg
  unsigned short* x_bf  = (unsigned short*)(ws + 0);
  unsigned short* wqkv  = (unsigned short*)(ws + (size_t)8 * 1024 * 1024);
  unsigned short* wo_bf = (unsigned short*)(ws + (size_t)14 * 1024 * 1024);
  unsigned short* qkv   = (unsigned short*)(ws + (size_t)16 * 1024 * 1024);
  unsigned short* ctx   = (unsigned short*)(ws + (size_t)40 * 1024 * 1024);
  unsigned short* vTg   = (unsigned short*)(ws + (size_t)48 * 1024 * 1024);
  unsigned short* po0   = x_bf;                       // aliases, stream-ordered safe
  float2*         ml    = (float2*)(ws + (size_t)8 * 1024 * 1024);

  convert_all<<<8192, 256, 0, stream>>>(x, Wq, Wk, Wv, Wo, x_bf, wqkv, wo_bf);

  dim3 g1(S_LEN / 128, (3 * DM) / 128);
  gemm_bt<unsigned short><<<g1, 256, 0, stream>>>(x_bf, wqkv, qkv, S_LEN, 3 * DM, DM);

  dim3 gt(S_LEN / 64, NH);
  transpose_v<<<gt, 256, 0, stream>>>(qkv, vTg);

  attn_split<<<1024, 256, 0, stream>>>(qkv, vTg, po0, ctx, ml);

  merge_parts<<<(S_LEN * NH) / 256, 256, 0, stream>>>(po0, ctx, ml);

  dim3 g3(S_LEN / 128, DM / 128);
  gemm_bt<float><<<g3, 256, 0, stream>>>(ctx, wo_bf, out, S_LEN, DM, DM);
}

// Round 9
// 242.776 us; speedup vs baseline: 1.5695x; 1.2125x over previous
//
#include <hip/hip_runtime.h>
#include <hip/hip_bf16.h>
#include <stdint.h>

#define S_LEN 4096
#define DM 1024
#define NH 16
#define DKH 64
#define LDQ (3 * DM)

typedef __attribute__((ext_vector_type(8))) __bf16 bf16x8;
typedef __attribute__((ext_vector_type(8))) short s16x8;
typedef __attribute__((ext_vector_type(4))) float f32x4;

__device__ inline unsigned short f2bf(float f) {
  unsigned int u = __builtin_bit_cast(unsigned int, f);
  u += 0x7fff + ((u >> 16) & 1);   // RNE
  return (unsigned short)(u >> 16);
}
__device__ inline float bf2f(unsigned short u) {
  return __builtin_bit_cast(float, (unsigned int)u << 16);
}
__device__ inline unsigned short f2bf_hw(float f) {   // v_cvt single-op path
  return __builtin_bit_cast(unsigned short, __float2bfloat16(f));
}

__device__ inline f32x4 mfma16(s16x8 a, s16x8 b, f32x4 c) {
  return __builtin_amdgcn_mfma_f32_16x16x32_bf16(
      __builtin_bit_cast(bf16x8, a), __builtin_bit_cast(bf16x8, b), c, 0, 0, 0);
}

__device__ inline void gld_lds16(const unsigned short* g, unsigned short* l) {
  __builtin_amdgcn_global_load_lds(
      (const __attribute__((address_space(1))) unsigned int*)g,
      (__attribute__((address_space(3))) unsigned int*)l, 16, 0, 0);
}

// one fused conversion pass: x + Wq/Wk/Wv (-> wqkv) + Wo (-> wo_bf)
__global__ __launch_bounds__(256) void convert_all(
    const float* __restrict__ x, const float* __restrict__ wq,
    const float* __restrict__ wk, const float* __restrict__ wv,
    const float* __restrict__ wo, unsigned short* __restrict__ x_bf,
    unsigned short* __restrict__ wqkv, unsigned short* __restrict__ wo_bf) {
  const int XF4 = (S_LEN * DM) / 4;
  const int WF4 = (DM * DM) / 4;
  int i = blockIdx.x * blockDim.x + threadIdx.x;
  const float* src;
  unsigned short* dst;
  int off;
  if (i < XF4) { src = x; dst = x_bf; off = i; }
  else {
    int j = i - XF4;
    if (j < WF4)          { src = wq; dst = wqkv;               off = j; }
    else if (j < 2 * WF4) { src = wk; dst = wqkv + DM * DM;     off = j - WF4; }
    else if (j < 3 * WF4) { src = wv; dst = wqkv + 2 * DM * DM; off = j - 2 * WF4; }
    else                  { src = wo; dst = wo_bf;              off = j - 3 * WF4; }
  }
  float4 v = reinterpret_cast<const float4*>(src)[off];
  ushort4 o;
  o.x = f2bf(v.x); o.y = f2bf(v.y); o.z = f2bf(v.z); o.w = f2bf(v.w);
  reinterpret_cast<ushort4*>(dst)[off] = o;
}

__device__ inline void storeC(unsigned short* C, size_t i, float v) { C[i] = f2bf(v); }
__device__ inline void storeC(float* C, size_t i, float v) { C[i] = v; }

// C[m][n] = sum_k A[m][k] * B[n][k]
template <typename OutT>
__global__ __launch_bounds__(256) void gemm_bt(const unsigned short* __restrict__ A,
                                               const unsigned short* __restrict__ B,
                                               OutT* __restrict__ C, int M, int N, int K) {
  __shared__ __align__(16) unsigned short lds_a[128 * 64];
  __shared__ __align__(16) unsigned short lds_b[128 * 64];
  const int tid = threadIdx.x;
  const int lane = tid & 63;
  const int w = tid >> 6;
  const int wr = w >> 1, wc = w & 1;
  const int l15 = lane & 15, lhi = lane >> 4;
  const int bm0 = blockIdx.x * 128, bn0 = blockIdx.y * 128;
  const int srow = lane >> 3;
  const int scol = (lane & 7) * 8;

  f32x4 acc[4][4] = {};

  for (int k0 = 0; k0 < K; k0 += 64) {
    __syncthreads();
#pragma unroll
    for (int i = 0; i < 4; ++i) {
      const int base = i * 2048 + w * 512;
      const int row = i * 32 + w * 8 + srow;
      gld_lds16(A + (size_t)(bm0 + row) * K + k0 + scol, lds_a + base);
      gld_lds16(B + (size_t)(bn0 + row) * K + k0 + scol, lds_b + base);
    }
    __syncthreads();
#pragma unroll
    for (int kk = 0; kk < 2; ++kk) {
      s16x8 af[4], bfr[4];
#pragma unroll
      for (int mi = 0; mi < 4; ++mi)
        af[mi] = *(const s16x8*)&lds_a[(wr * 64 + mi * 16 + l15) * 64 + kk * 32 + lhi * 8];
#pragma unroll
      for (int ni = 0; ni < 4; ++ni)
        bfr[ni] = *(const s16x8*)&lds_b[(wc * 64 + ni * 16 + l15) * 64 + kk * 32 + lhi * 8];
#pragma unroll
      for (int mi = 0; mi < 4; ++mi)
#pragma unroll
        for (int ni = 0; ni < 4; ++ni)
          acc[mi][ni] = mfma16(af[mi], bfr[ni], acc[mi][ni]);
    }
  }
#pragma unroll
  for (int mi = 0; mi < 4; ++mi)
#pragma unroll
    for (int ni = 0; ni < 4; ++ni)
#pragma unroll
      for (int r = 0; r < 4; ++r) {
        int row = bm0 + wr * 64 + mi * 16 + lhi * 4 + r;
        int col = bn0 + wc * 64 + ni * 16 + l15;
        storeC(C, (size_t)row * N + col, acc[mi][ni][r]);
      }
}

// V^T per head: vTg[(h*DKH + dk)*S + s] = QKV[s][2*DM + h*DKH + dk]
__global__ __launch_bounds__(256) void transpose_v(const unsigned short* __restrict__ QKV,
                                                   unsigned short* __restrict__ vTg) {
  const int s0 = blockIdx.x * 64;
  const int h = blockIdx.y;
  __shared__ __align__(16) unsigned short t[64][72];
  const int r = threadIdx.x >> 2;
  const int c = (threadIdx.x & 3) * 16;
  const unsigned short* src = QKV + (size_t)(s0 + r) * LDQ + 2 * DM + h * DKH + c;
#pragma unroll
  for (int j = 0; j < 16; j += 4)
    *(ushort4*)&t[r][c + j] = *(const ushort4*)(src + j);
  __syncthreads();
  const int d = threadIdx.x >> 2;
  const int sc = (threadIdx.x & 3) * 16;
  unsigned short* dst = vTg + (size_t)(h * DKH + d) * S_LEN + s0 + sc;
#pragma unroll
  for (int j = 0; j < 16; j += 4) {
    ushort4 v;
    v.x = t[sc + j + 0][d]; v.y = t[sc + j + 1][d];
    v.z = t[sc + j + 2][d]; v.w = t[sc + j + 3][d];
    *(ushort4*)(dst + j) = v;
  }
}

// Stage one 64x64 K-tile + V^T-tile into LDS (128-thread block, 4 strips each).
// Linear LDS dest; SOURCE column pre-swizzled so reads at col^((row&7)*8)
// return the true (row,col).
__device__ inline void stage_kv(const unsigned short* __restrict__ Kp,
                                const unsigned short* __restrict__ vTg,
                                unsigned short* lk, unsigned short* lv,
                                int kb, int h, int tid) {
  const int w = tid >> 6, l = tid & 63;
  const int sub = l >> 3;                       // 0..7
  const int src_col = 8 * ((l & 7) ^ sub);      // pre-swizzled source column
#pragma unroll
  for (int i = 0; i < 4; ++i) {
    const int rbase = i * 16 + w * 8;           // multiple of 8
    const int row = rbase + sub;
    gld_lds16(Kp + (size_t)(kb + row) * LDQ + h * DKH + src_col, lk + rbase * 64);
    gld_lds16(vTg + (size_t)(h * DKH + row) * S_LEN + kb + src_col, lv + rbase * 64);
  }
}

// One k-tile, one wave, 32 q-rows. Swapped QK^T: mfma(K,Q) -> lane holds
// P[key=kb+st*16+lhi*4+r][q=qrow0+qb*16+l15]; row stats reduce in-lane + 2 shfl.
// PV computes O^T via mfma(V^T, P): o[n][qb] = C[dk][q].
template <bool MASK>
__device__ inline void attn_tile2(const unsigned short* __restrict__ lk,
                                  const unsigned short* __restrict__ lv,
                                  unsigned short (*pb)[64], const s16x8 qf[2][2],
                                  int kb, int qrow0, int l15, int lhi,
                                  f32x4 o[4][2], float m_r[2], float l_r[2]) {
  const int sw = (l15 & 7) * 8;   // XOR swizzle for lane-row LDS reads
  f32x4 sf[2][4];
#pragma unroll
  for (int qb = 0; qb < 2; ++qb)
#pragma unroll
    for (int st = 0; st < 4; ++st) {
      f32x4 acc = {};
#pragma unroll
      for (int kk = 0; kk < 2; ++kk) {
        s16x8 kf = *(const s16x8*)&lk[(st * 16 + l15) * 64 + ((kk * 32 + lhi * 8) ^ sw)];
        acc = mfma16(kf, qf[qb][kk], acc);
      }
      sf[qb][st] = acc;
    }
  if (MASK) {
#pragma unroll
    for (int qb = 0; qb < 2; ++qb) {
      const int qrow = qrow0 + qb * 16 + l15;
#pragma unroll
      for (int st = 0; st < 4; ++st)
#pragma unroll
        for (int r = 0; r < 4; ++r)
          if (kb + st * 16 + lhi * 4 + r > qrow) sf[qb][st][r] = -1e30f;
    }
  }
  // per-lane row max: in-lane tree over 16 + 2 shfl (d=16, 32)
  float mt[2];
#pragma unroll
  for (int qb = 0; qb < 2; ++qb) {
    float a0 = fmaxf(fmaxf(sf[qb][0][0], sf[qb][0][1]), fmaxf(sf[qb][0][2], sf[qb][0][3]));
    float a1 = fmaxf(fmaxf(sf[qb][1][0], sf[qb][1][1]), fmaxf(sf[qb][1][2], sf[qb][1][3]));
    float a2 = fmaxf(fmaxf(sf[qb][2][0], sf[qb][2][1]), fmaxf(sf[qb][2][2], sf[qb][2][3]));
    float a3 = fmaxf(fmaxf(sf[qb][3][0], sf[qb][3][1]), fmaxf(sf[qb][3][2], sf[qb][3][3]));
    float mx = fmaxf(fmaxf(a0, a1), fmaxf(a2, a3));
    mx = fmaxf(mx, __shfl_xor(mx, 16));
    mx = fmaxf(mx, __shfl_xor(mx, 32));
    mt[qb] = mx;
  }
  // defer-max (T13)
  const bool anyg = __any((mt[0] > m_r[0] + 8.f) | (mt[1] > m_r[1] + 8.f));
  float alpha[2];
  if (anyg) {
#pragma unroll
    for (int qb = 0; qb < 2; ++qb) {
      const float mn = fmaxf(m_r[qb], mt[qb]);
      alpha[qb] = __expf(m_r[qb] - mn);
      m_r[qb] = mn;
    }
  }
  // exp + in-lane row sum + 2 shfl
#pragma unroll
  for (int qb = 0; qb < 2; ++qb) {
    const float m = m_r[qb];
#pragma unroll
    for (int st = 0; st < 4; ++st) {
      f32x4 t = sf[qb][st];
      t[0] = __expf(t[0] - m); t[1] = __expf(t[1] - m);
      t[2] = __expf(t[2] - m); t[3] = __expf(t[3] - m);
      sf[qb][st] = t;
    }
    float s0 = (sf[qb][0][0] + sf[qb][0][1]) + (sf[qb][0][2] + sf[qb][0][3]);
    float s1 = (sf[qb][1][0] + sf[qb][1][1]) + (sf[qb][1][2] + sf[qb][1][3]);
    float s2 = (sf[qb][2][0] + sf[qb][2][1]) + (sf[qb][2][2] + sf[qb][2][3]);
    float s3 = (sf[qb][3][0] + sf[qb][3][1]) + (sf[qb][3][2] + sf[qb][3][3]);
    float rs = (s0 + s1) + (s2 + s3);
    rs += __shfl_xor(rs, 16);
    rs += __shfl_xor(rs, 32);
    l_r[qb] = (anyg ? l_r[qb] * alpha[qb] : l_r[qb]) + rs;
  }
  if (anyg) {
#pragma unroll
    for (int n = 0; n < 4; ++n)
#pragma unroll
      for (int qb = 0; qb < 2; ++qb) {
        f32x4 t = o[n][qb];
        t[0] *= alpha[qb]; t[1] *= alpha[qb]; t[2] *= alpha[qb]; t[3] *= alpha[qb];
        o[n][qb] = t;
      }
  }
  // P -> wave-private swizzled LDS: 4 contiguous keys per lane -> b64 writes
#pragma unroll
  for (int qb = 0; qb < 2; ++qb) {
    const int row = qb * 16 + l15;
    const int rsw = (row & 7) * 8;
#pragma unroll
    for (int st = 0; st < 4; ++st) {
      ushort4 pk;
      pk.x = f2bf_hw(sf[qb][st][0]); pk.y = f2bf_hw(sf[qb][st][1]);
      pk.z = f2bf_hw(sf[qb][st][2]); pk.w = f2bf_hw(sf[qb][st][3]);
      *(ushort4*)&pb[row][(st * 16 + lhi * 4) ^ rsw] = pk;
    }
  }
  // O^T += V^T * P  (A = V^T rows=dk, B = P rows=q)
#pragma unroll
  for (int kk = 0; kk < 2; ++kk) {
    s16x8 pa[2];
#pragma unroll
    for (int qb = 0; qb < 2; ++qb)
      pa[qb] = *(const s16x8*)&pb[qb * 16 + l15][(kk * 32 + lhi * 8) ^ sw];
#pragma unroll
    for (int n = 0; n < 4; ++n) {
      s16x8 vb = *(const s16x8*)&lv[(n * 16 + l15) * 64 + ((kk * 32 + lhi * 8) ^ sw)];
#pragma unroll
      for (int qb = 0; qb < 2; ++qb)
        o[n][qb] = mfma16(vb, pa[qb], o[n][qb]);
    }
  }
}

// 1024 blocks x 128 threads. Block = (pair p, seg b, head). Members:
// (qt=p, seg=b) then (qt=63-p, seg=1-b); each ~33 k-tiles (uniform).
// 2 waves x 32 q-rows. LDS 40960 B -> 4 blocks/CU.
__global__ __launch_bounds__(128, 2) void attn_split2(const unsigned short* __restrict__ QKV,
                                                      const unsigned short* __restrict__ vTg,
                                                      unsigned short* __restrict__ po0,
                                                      unsigned short* __restrict__ po1,
                                                      float2* __restrict__ ml) {
  const int flat = blockIdx.x;          // 0..1023
  const int xcd = flat & 7;
  const int t = flat >> 3;              // 0..127
  const int h = 2 * xcd + (t & 1);      // 2 heads per XCD (L2 locality)
  const int u = t >> 1;                 // 0..63
  const int p = u & 31;
  const int b = u >> 5;
  const int tid = threadIdx.x;
  const int lane = tid & 63, w = tid >> 6;
  const int l15 = lane & 15, lhi = lane >> 4;

  __shared__ __align__(16) unsigned short lk[2][64 * 64];    // 16 KiB
  __shared__ __align__(16) unsigned short lv[2][64 * 64];    // 16 KiB
  __shared__ __align__(16) unsigned short pbuf[2][32][64];   //  8 KiB -> 40960 total
  unsigned short (*pb)[64] = pbuf[w];

  const unsigned short* Qp = QKV;
  const unsigned short* Kp = QKV + DM;

#pragma unroll 1
  for (int mem = 0; mem < 2; ++mem) {
    const int qt  = mem ? (63 - p) : p;
    const int seg = mem ? (1 - b) : b;
    const int s0 = (qt + 2) >> 1;
    const int ks = seg ? s0 : 0;
    const int ke = seg ? (qt + 1) : s0;
    const int qrow0 = qt * 64 + w * 32;

    s16x8 qf[2][2];
#pragma unroll
    for (int qb = 0; qb < 2; ++qb)
#pragma unroll
      for (int kk = 0; kk < 2; ++kk) {
        s16x8 q = *(const s16x8*)&Qp[(size_t)(qrow0 + qb * 16 + l15) * LDQ + h * DKH + kk * 32 + lhi * 8];
#pragma unroll
        for (int e = 0; e < 8; ++e)
          q[e] = (short)f2bf(bf2f((unsigned short)q[e]) * 0.125f);  // fold 1/sqrt(64), exact
        qf[qb][kk] = q;
      }
    f32x4 o[4][2] = {};
    float m_r[2] = {-1e30f, -1e30f}, l_r[2] = {0.f, 0.f};

    __syncthreads();               // buffers free (previous member done reading)
    if (ks < ke) {
      stage_kv(Kp, vTg, lk[0], lv[0], ks * 64, h, tid);
      int cur = 0;
#pragma unroll 1
      for (int kbi = ks; kbi < ke; ++kbi) {
        __syncthreads();           // staged buf[cur] ready (vmcnt drained at barrier)
        if (kbi + 1 < ke)
          stage_kv(Kp, vTg, lk[cur ^ 1], lv[cur ^ 1], (kbi + 1) * 64, h, tid);
        if (kbi == qt)
          attn_tile2<true>(lk[cur], lv[cur], pb, qf, kbi * 64, qrow0, l15, lhi, o, m_r, l_r);
        else
          attn_tile2<false>(lk[cur], lv[cur], pb, qf, kbi * 64, qrow0, l15, lhi, o, m_r, l_r);
        cur ^= 1;
      }
    }
    // epilogue: unnormalized partial O (bf16, from O^T regs) + (m, l)
    unsigned short* po = seg ? po1 : po0;
#pragma unroll
    for (int qb = 0; qb < 2; ++qb) {
      const int qrow = qrow0 + qb * 16 + l15;
#pragma unroll
      for (int n = 0; n < 4; ++n) {
        ushort4 ov;
        ov.x = f2bf_hw(o[n][qb][0]); ov.y = f2bf_hw(o[n][qb][1]);
        ov.z = f2bf_hw(o[n][qb][2]); ov.w = f2bf_hw(o[n][qb][3]);
        *(ushort4*)(po + (size_t)qrow * DM + h * DKH + n * 16 + lhi * 4) = ov;
      }
    }
    if (lhi == 0) {
#pragma unroll
      for (int qb = 0; qb < 2; ++qb) {
        const int qrow = qrow0 + qb * 16 + l15;
        ml[(qrow * NH + h) * 2 + seg] = make_float2(m_r[qb], l_r[qb]);
      }
    }
  }
}

// merge: ctx = (o0*e^{m0-m} + o1*e^{m1-m}) / (l0*e^{m0-m} + l1*e^{m1-m}); po1 IS ctx.
__global__ __launch_bounds__(256) void merge_parts(const unsigned short* __restrict__ po0,
                                                   unsigned short* __restrict__ po1_ctx,
                                                   const float2* __restrict__ ml) {
  const int i = blockIdx.x * blockDim.x + threadIdx.x;   // 0..65535
  const int row = i >> 4, h = i & 15;
  const float2 ml0 = ml[i * 2 + 0];
  const float2 ml1 = ml[i * 2 + 1];
  const float m = fmaxf(ml0.x, ml1.x);
  const float f0 = __expf(ml0.x - m);
  const float f1 = __expf(ml1.x - m);
  const float rl = 1.f / (ml0.y * f0 + ml1.y * f1);
  const size_t base = (size_t)row * DM + h * DKH;
#pragma unroll
  for (int c = 0; c < DKH; c += 8) {
    s16x8 a = *(const s16x8*)(po0 + base + c);
    s16x8 bb = *(const s16x8*)(po1_ctx + base + c);
    s16x8 out;
#pragma unroll
    for (int j = 0; j < 8; ++j)
      out[j] = (short)f2bf_hw((bf2f((unsigned short)a[j]) * f0 +
                               bf2f((unsigned short)bb[j]) * f1) * rl);
    *(s16x8*)(po1_ctx + base + c) = out;
  }
}

extern "C" void kernel_launch(void* const* d_in, const int* in_sizes, int n_in,
                              void* d_out, int out_size, void* d_ws, size_t ws_size,
                              hipStream_t stream) {
  const float* x  = (const float*)d_in[0];
  const float* Wq = (const float*)d_in[1];
  const float* Wk = (const float*)d_in[2];
  const float* Wv = (const float*)d_in[3];
  const float* Wo = (const float*)d_in[4];
  float* out = (float*)d_out;
  char* ws = (char*)d_ws;

  // [0,8): x_bf -> reused as partial-o seg0   [8,14): wqkv -> [8,9) reused as ml
  // [14,16): wo_bf   [16,40): qkv   [40,48): ctx == partial-o seg1   [48,64): vTg
  unsigned short* x_bf  = (unsigned short*)(ws + 0);
  unsigned short* wqkv  = (unsigned short*)(ws + (size_t)8 * 1024 * 1024);
  unsigned short* wo_bf = (unsigned short*)(ws + (size_t)14 * 1024 * 1024);
  unsigned short* qkv   = (unsigned short*)(ws + (size_t)16 * 1024 * 1024);
  unsigned short* ctx   = (unsigned short*)(ws + (size_t)40 * 1024 * 1024);
  unsigned short* vTg   = (unsigned short*)(ws + (size_t)48 * 1024 * 1024);
  unsigned short* po0   = x_bf;
  float2*         ml    = (float2*)(ws + (size_t)8 * 1024 * 1024);

  convert_all<<<8192, 256, 0, stream>>>(x, Wq, Wk, Wv, Wo, x_bf, wqkv, wo_bf);

  dim3 g1(S_LEN / 128, (3 * DM) / 128);
  gemm_bt<unsigned short><<<g1, 256, 0, stream>>>(x_bf, wqkv, qkv, S_LEN, 3 * DM, DM);

  dim3 gt(S_LEN / 64, NH);
  transpose_v<<<gt, 256, 0, stream>>>(qkv, vTg);

  attn_split2<<<1024, 128, 0, stream>>>(qkv, vTg, po0, ctx, ml);

  merge_parts<<<(S_LEN * NH) / 256, 256, 0, stream>>>(po0, ctx, ml);

  dim3 g3(S_LEN / 128, DM / 128);
  gemm_bt<float><<<g3, 256, 0, stream>>>(ctx, wo_bf, out, S_LEN, DM, DM);
}